// Round 16
// baseline (4277.301 us; speedup 1.0000x reference)
//
#include <hip/hip_runtime.h>
#include <stdint.h>

// LSTM forward, B=32 T=2048 D=512 H=512 G=2048.
// Round 16 = r14 (best verified: 3.71ms lstm_rec) + one bounded tweak:
//   non-elem waves s_sleep(3) (~192cy) before their early poll so the poll
//   return lands after publishes become visible (L2 RTT ~300cy) instead of
//   guaranteed-stale. Worst case bounded at +192cy/step.
// r14 recap:
//   - XCD-verified placement: s_getreg(HW_REG_XCC_ID) + atomic claim table
//     -> each sync domain (batch-group, 16 WGs) lives on ONE XCD.
//   - L/M split exchange: L buffer published with PLAIN stores only (line
//     stays live in the shared per-XCD L2; sc0 polls hit it ~300cy); M
//     buffer (different lines) published sc0sc1 (MALL) as the correctness
//     fallback for misplaced WGs. r13 lesson: same-address sc0sc1 mirror
//     kills the local line - buffers MUST be separate.
//   - Tagged dwords (lo16 bf16 h | hi16 step), double-buffered slots,
//     tag+payload share a dword => no fences anywhere.
//   - Deferred out-stores (r12): {fa,h,ga} stored at top of NEXT iteration
//     so retry VMWAIT(0) never drains HBM store acks.
//   - 2 barriers/step (pacing is load-bearing: r15's zero-barrier variant
//     congestion-collapsed into a timeout).

#define B_ 32
#define T_ 2048
#define D_ 512
#define H_ 512
#define G_ 2048
#define NCG 16
#define NBG 8

typedef __attribute__((ext_vector_type(4))) float f32x4;
typedef __attribute__((ext_vector_type(8))) short bf16x8;
typedef __attribute__((ext_vector_type(4))) unsigned int uint4v;
typedef __attribute__((ext_vector_type(2))) unsigned int uint2v;

__device__ __forceinline__ unsigned short f2bf(float f) {
  union { float f; unsigned int u; } v; v.f = f;
  unsigned int r = (v.u + 0x7FFFu + ((v.u >> 16) & 1u)) >> 16;
  return (unsigned short)r;
}
__device__ __forceinline__ float bf2f(unsigned short s) {
  union { unsigned int u; float f; } v; v.u = ((unsigned int)s) << 16;
  return v.f;
}
__device__ __forceinline__ float sigm(float x) { return 1.0f / (1.0f + __expf(-x)); }
__device__ __forceinline__ float tanh_(float x) { return 1.0f - 2.0f / (__expf(2.0f * x) + 1.0f); }

__device__ __forceinline__ void store_x4_coherent(unsigned int* p, uint4v v) {
  asm volatile("global_store_dwordx4 %0, %1, off sc0 sc1" :: "v"(p), "v"(v) : "memory");
}

#define BARRIER_LGKM()                                          \
  do {                                                          \
    asm volatile("s_waitcnt lgkmcnt(0)" ::: "memory");          \
    __builtin_amdgcn_sched_barrier(0);                          \
    __builtin_amdgcn_s_barrier();                               \
    __builtin_amdgcn_sched_barrier(0);                          \
  } while (0)

#define VMWAIT(N)                                               \
  do { asm volatile("s_waitcnt vmcnt(" #N ")" ::: "memory");    \
       __builtin_amdgcn_sched_barrier(0); } while (0)

// ---------------- Phase 1: convert inputs + seed/clear L,M + ctrl ----------
__global__ __launch_bounds__(256) void prep_kernel(
    const float* __restrict__ x, const float* __restrict__ w_ih,
    const float* __restrict__ hx,
    unsigned short* __restrict__ x_bf, unsigned short* __restrict__ w_bf,
    unsigned int* __restrict__ h_tag, unsigned int* __restrict__ ctrl) {
  const int NX8 = (B_ * T_ * D_) / 8;   // 4,194,304
  const int NWT8 = (G_ * D_) / 8;       // 131,072
  const int A = NX8 + NWT8;
  int i = blockIdx.x * 256 + threadIdx.x;
  if (i < NX8) {
    float4 a = reinterpret_cast<const float4*>(x)[i * 2];
    float4 b = reinterpret_cast<const float4*>(x)[i * 2 + 1];
    uint4v v;
    v[0] = (unsigned)f2bf(a.x) | ((unsigned)f2bf(a.y) << 16);
    v[1] = (unsigned)f2bf(a.z) | ((unsigned)f2bf(a.w) << 16);
    v[2] = (unsigned)f2bf(b.x) | ((unsigned)f2bf(b.y) << 16);
    v[3] = (unsigned)f2bf(b.z) | ((unsigned)f2bf(b.w) << 16);
    reinterpret_cast<uint4v*>(x_bf)[i] = v;
  } else if (i < A) {
    int j = i - NX8;
    float4 a = reinterpret_cast<const float4*>(w_ih)[j * 2];
    float4 b = reinterpret_cast<const float4*>(w_ih)[j * 2 + 1];
    uint4v v;
    v[0] = (unsigned)f2bf(a.x) | ((unsigned)f2bf(a.y) << 16);
    v[1] = (unsigned)f2bf(a.z) | ((unsigned)f2bf(a.w) << 16);
    v[2] = (unsigned)f2bf(b.x) | ((unsigned)f2bf(b.y) << 16);
    v[3] = (unsigned)f2bf(b.z) | ((unsigned)f2bf(b.w) << 16);
    reinterpret_cast<uint4v*>(w_bf)[j] = v;
  } else if (i < A + 2048) {
    int j = i - A;  // seed slot 0 from hx, tag 0 (L plain, M sc0sc1)
    float4 a = reinterpret_cast<const float4*>(hx)[j * 2];
    float4 b = reinterpret_cast<const float4*>(hx)[j * 2 + 1];
    uint4v v0, v1;
    v0[0] = f2bf(a.x); v0[1] = f2bf(a.y); v0[2] = f2bf(a.z); v0[3] = f2bf(a.w);
    v1[0] = f2bf(b.x); v1[1] = f2bf(b.y); v1[2] = f2bf(b.z); v1[3] = f2bf(b.w);
    unsigned int* pL = h_tag + j * 8;
    unsigned int* pM = h_tag + 32768 + j * 8;
    *reinterpret_cast<uint4v*>(pL) = v0;
    *reinterpret_cast<uint4v*>(pL + 4) = v1;
    store_x4_coherent(pM, v0);
    store_x4_coherent(pM + 4, v1);
  } else if (i < A + 4096) {
    int j = i - A - 2048;  // clear slot 1 (L plain, M sc0sc1)
    unsigned int* pL = h_tag + 16384 + j * 8;
    unsigned int* pM = h_tag + 49152 + j * 8;
    uint4v z = {0u, 0u, 0u, 0u};
    *reinterpret_cast<uint4v*>(pL) = z;
    *reinterpret_cast<uint4v*>(pL + 4) = z;
    store_x4_coherent(pM, z);
    store_x4_coherent(pM + 4, z);
  } else {
    int j = i - A - 4096;  // clear ctrl (counters + claim table), 256 dwords
    unsigned int* p = ctrl + j;
    unsigned int z = 0u;
    asm volatile("global_store_dword %0, %1, off sc0 sc1" :: "v"(p), "v"(z) : "memory");
  }
}

// ---------------- Phase 2: gx GEMM (r12 layout, NCG=16) ----------------
__global__ __launch_bounds__(256, 2) void gemm_gx(
    const unsigned short* __restrict__ x_bf, const unsigned short* __restrict__ w_bf,
    const float* __restrict__ b_ih, const float* __restrict__ b_hh,
    unsigned short* __restrict__ gx_ws) {
  __shared__ unsigned short As[128 * 40];
  __shared__ unsigned short Bs[128 * 40];
  __shared__ unsigned short Eg[128 * 136];
  const int bid = blockIdx.x;
  const int cb = bid & 15, rb = bid >> 4;
  const int r0 = rb * 128, c0 = cb * 128;
  const int tid = threadIdx.x;
  const int lane = tid & 63;
  const int w = tid >> 6;
  const int qr = (w >> 1) * 64, qc = (w & 1) * 64;
  f32x4 acc[4][4] = {};

  for (int kt = 0; kt < 16; ++kt) {
    const int k0 = kt * 32;
    uint4v av[2], bv[2];
#pragma unroll
    for (int c = 0; c < 2; ++c) {
      int flat = c * 256 + tid;
      int row = flat >> 2, q = flat & 3;
      av[c] = *reinterpret_cast<const uint4v*>(x_bf + (size_t)(r0 + row) * 512 + k0 + q * 8);
      bv[c] = *reinterpret_cast<const uint4v*>(w_bf + (size_t)(c0 + row) * 512 + k0 + q * 8);
    }
    __syncthreads();
#pragma unroll
    for (int c = 0; c < 2; ++c) {
      int flat = c * 256 + tid;
      int row = flat >> 2, q = flat & 3;
      *reinterpret_cast<uint4v*>(&As[row * 40 + q * 8]) = av[c];
      *reinterpret_cast<uint4v*>(&Bs[row * 40 + q * 8]) = bv[c];
    }
    __syncthreads();
    bf16x8 af[4], bfr[4];
#pragma unroll
    for (int mt = 0; mt < 4; ++mt)
      af[mt] = *reinterpret_cast<const bf16x8*>(&As[(qr + mt * 16 + (lane & 15)) * 40 + (lane >> 4) * 8]);
#pragma unroll
    for (int nt = 0; nt < 4; ++nt)
      bfr[nt] = *reinterpret_cast<const bf16x8*>(&Bs[(qc + nt * 16 + (lane & 15)) * 40 + (lane >> 4) * 8]);
#pragma unroll
    for (int mt = 0; mt < 4; ++mt)
#pragma unroll
      for (int nt = 0; nt < 4; ++nt)
        acc[mt][nt] = __builtin_amdgcn_mfma_f32_16x16x32_bf16(af[mt], bfr[nt], acc[mt][nt], 0, 0, 0);
  }
  __syncthreads();
#pragma unroll
  for (int nt = 0; nt < 4; ++nt) {
    int cg = c0 + qc + nt * 16 + (lane & 15);
    float bias = b_ih[cg] + b_hh[cg];
#pragma unroll
    for (int mt = 0; mt < 4; ++mt)
#pragma unroll
      for (int j = 0; j < 4; ++j) {
        int tr = qr + mt * 16 + (lane >> 4) * 4 + j;
        int cl = qc + nt * 16 + (lane & 15);
        Eg[tr * 136 + cl] = f2bf(acc[mt][nt][j] + bias);
      }
  }
  __syncthreads();
  const int b = r0 >> 11;
  const int g = c0 >> 9;
  const int t0 = r0 & 2047;
  const int nw0 = (c0 & 511) >> 5;
  const int bg = b >> 2, bq = b & 3;
  for (int c = tid; c < 512; c += 256) {
    int tr = c >> 2, nwi = c & 3;
    size_t dst = (((size_t)(t0 + tr) * NBG + bg) * NCG + (nw0 + nwi)) * 512 + bq * 128 + g * 32;
    const unsigned short* src = &Eg[tr * 136 + nwi * 32];
#pragma unroll
    for (int q = 0; q < 4; ++q)
      *reinterpret_cast<uint4v*>(gx_ws + dst + q * 8) =
          *reinterpret_cast<const uint4v*>(src + q * 8);
  }
}

// ---------------- Phase 3: recurrence ----------------
#define POLLF(PP) \
  asm volatile("global_load_dwordx4 %0, %1, off sc0" : "=v"(hv) : "v"(PP))
#define POLLS(PP) \
  asm volatile("global_load_dwordx4 %0, %1, off sc0 sc1" : "=v"(hv) : "v"(PP))

__global__ __launch_bounds__(512) void lstm_rec(
    const float* __restrict__ cx, const float* __restrict__ w_hh,
    const unsigned short* __restrict__ gx_ws, unsigned int* __restrict__ h_tag,
    unsigned int* __restrict__ ctrl, float* __restrict__ out) {
  const int tid = threadIdx.x;
  const int lane = tid & 63;
  const int w = tid >> 6;
  __shared__ unsigned short As[4 * 536];   // h rows (bf16), stride 536
  __shared__ float Gt2[8 * 64];            // [tile n][cl*4+bq]
  __shared__ unsigned short GxL[2][512];   // gx dbuf [bq][g][jl]
  __shared__ int sdr[2];

  // ---- dynamic XCD-grouped slot claim: domain = this WG's real XCD ----
  if (tid == 0) {
    int xcd;
    asm volatile("s_getreg_b32 %0, hwreg(HW_REG_XCC_ID)" : "=s"(xcd));
    xcd &= 7;
    unsigned int* cnt = ctrl;        // [8] per-XCD counters
    unsigned int* clm = ctrl + 8;    // [128] claim flags
    int slot = -1;
    unsigned role = atomicAdd(&cnt[xcd], 1u);
    if (role < 16u) {
      if (atomicCAS(&clm[xcd * 16 + role], 0u, 1u) == 0u)
        slot = xcd * 16 + (int)role;
    }
    while (slot < 0) {               // overflow: steal any free slot
      for (int s = 0; s < 128 && slot < 0; ++s)
        if (atomicCAS(&clm[s], 0u, 1u) == 0u) slot = s;
    }
    sdr[0] = slot >> 4;   // bg (domain == XCD when balanced)
    sdr[1] = slot & 15;   // nw (col-group)
  }
  __syncthreads();
  const int bg = sdr[0];
  const int nw = sdr[1];
  const int gi = w >> 1;
  const int half = w & 1;
  const bool ownq = (((tid & 127) >> 3) == nw);  // poll dwords are own cols

  // B-frags: one N-tile (16 gate-cols), full K=512 -> 16 frags = 64 VGPR
  bf16x8 breg[16];
  {
    int gcol = gi * 512 + nw * 32 + half * 16 + (lane & 15);
    const float* wrow = w_hh + (size_t)gcol * 512;
#pragma unroll
    for (int kk = 0; kk < 16; ++kk) {
      int k = kk * 32 + (lane >> 4) * 8;
      float4 f0 = *reinterpret_cast<const float4*>(wrow + k);
      float4 f1 = *reinterpret_cast<const float4*>(wrow + k + 4);
      uint4v v;
      v[0] = (unsigned)f2bf(f0.x) | ((unsigned)f2bf(f0.y) << 16);
      v[1] = (unsigned)f2bf(f0.z) | ((unsigned)f2bf(f0.w) << 16);
      v[2] = (unsigned)f2bf(f1.x) | ((unsigned)f2bf(f1.y) << 16);
      v[3] = (unsigned)f2bf(f1.z) | ((unsigned)f2bf(f1.w) << 16);
      breg[kk] = __builtin_bit_cast(bf16x8, v);
    }
  }
  // elementwise ownership (waves 0,1): bq=lane&3, cl=lane>>2, jl=w*16+cl
  const int bq = lane & 3;
  const int cl = lane >> 2;
  const int jl = (w & 1) * 16 + cl;
  const int col = nw * 32 + jl;
  const int bno = bg * 4 + bq;
  float c = 0.0f;
  if (w < 2) {
    c = cx[bno * 512 + col];
    asm volatile("" :: "v"(c));
  }

  // L buffer (local, plain): slots at 0 / 16384. M buffer (MALL, sc0sc1):
  // slots at 32768 / 49152. Different cache lines.
  const unsigned int* pollL0 = h_tag + bg * 2048 + tid * 4;
  const unsigned int* pollL1 = pollL0 + 16384;
  const unsigned int* pollM0 = pollL0 + 32768;
  const unsigned int* pollM1 = pollL0 + 49152;
  unsigned int* pubL0 = h_tag + bno * 512 + col;
  unsigned int* pubL1 = pubL0 + 16384;
  unsigned int* pubM0 = pubL0 + 32768;
  unsigned int* pubM1 = pubL0 + 49152;
  const unsigned short* gx_base = gx_ws + ((size_t)bg * NCG + nw) * 512;
  const size_t GXT = (size_t)NBG * NCG * 512;
  const size_t BTH = (size_t)B_ * T_ * H_;

  uint4v hv;
  uint4v gxr;
  float pfa = 0.0f, ph = 0.0f, pga = 0.0f;  // deferred out values

  // ---- prologue: gx(0) + slow poll t=0 on M (seeded sc0sc1, remote)
  if (w == 0)
    asm volatile("global_load_dwordx4 %0, %1, off"
                 : "=v"(gxr) : "v"(gx_base + lane * 8));
  {
    POLLS(pollM0);
    VMWAIT(0);
    unsigned bad = (hv[0] >> 16) | (hv[1] >> 16) | (hv[2] >> 16) | (hv[3] >> 16);
    int guard = 0;
    while (bad) {
      POLLS(pollM0);
      VMWAIT(0);
      bad = (hv[0] >> 16) | (hv[1] >> 16) | (hv[2] >> 16) | (hv[3] >> 16);
      if (++guard > (1 << 20)) break;
    }
    uint2v pk;
    pk[0] = (hv[0] & 0xffffu) | (hv[1] << 16);
    pk[1] = (hv[2] & 0xffffu) | (hv[3] << 16);
    *reinterpret_cast<uint2v*>(&As[(tid >> 7) * 536 + (tid & 127) * 4]) = pk;
  }
  if (w == 0)
    *reinterpret_cast<uint4v*>(&GxL[0][lane * 8]) = __builtin_bit_cast(uint4v, gxr);

  for (int t = 0; t < T_; ++t) {
    BARRIER_LGKM();  // A: As + GxL[t&1] ready
    const bool more = (t + 1 < T_);
    // deferred out-stores for step t-1 (age across MFMA + barriers)
    if (w < 2 && t) {
      size_t bo = (size_t)bno * (T_ * H_) + (size_t)(t - 1) * H_ + col;
      asm volatile("global_store_dword %0, %1, off" :: "v"(out + bo), "v"(pfa) : "memory");
      asm volatile("global_store_dword %0, %1, off"
                   :: "v"(out + BTH + bo), "v"(ph) : "memory");
      asm volatile("global_store_dword %0, %1, off"
                   :: "v"(out + 2 * BTH + bo), "v"(pga) : "memory");
    }
    if (w == 0 && more)
      asm volatile("global_load_dwordx4 %0, %1, off"
                   : "=v"(gxr) : "v"(gx_base + (size_t)(t + 1) * GXT + lane * 8));
    // ---- MFMA: full K=512, one N-tile per wave; 2 independent chains
    f32x4 a0 = {}, a1 = {};
#pragma unroll
    for (int kk = 0; kk < 16; kk += 2) {
      bf16x8 af0 = *reinterpret_cast<const bf16x8*>(
          &As[(lane & 3) * 536 + kk * 32 + (lane >> 4) * 8]);
      bf16x8 af1 = *reinterpret_cast<const bf16x8*>(
          &As[(lane & 3) * 536 + (kk + 1) * 32 + (lane >> 4) * 8]);
      a0 = __builtin_amdgcn_mfma_f32_16x16x32_bf16(af0, breg[kk], a0, 0, 0, 0);
      a1 = __builtin_amdgcn_mfma_f32_16x16x32_bf16(af1, breg[kk + 1], a1, 0, 0, 0);
    }
    if (lane < 16) {
      f32x4 s4 = a0 + a1;  // C rows 0-3 = batches 0-3, col = lane
      *reinterpret_cast<f32x4*>(&Gt2[w * 64 + lane * 4]) = s4;
    }
    BARRIER_LGKM();  // B: Gt2 complete; As(t) dead from here
    const unsigned int* pollL = ((t + 1) & 1) ? pollL1 : pollL0;
    const unsigned int* pollM = ((t + 1) & 1) ? pollM1 : pollM0;
    if (more && !ownq) {
      // non-elem waves: delay poll issue ~192cy so its return lands after
      // publishes are visible (L2 RTT ~300cy) -> first check succeeds.
      if (w >= 2) __builtin_amdgcn_s_sleep(3);
      POLLF(pollL);  // early fast poll (L, local L2)
    }
    if (w < 2) {
      // ---- elementwise (waves 0,1): 128 outputs
      const int gxb = t & 1;
      float s0 = Gt2[(0 * 2 + w) * 64 + lane] + bf2f(GxL[gxb][bq * 128 + 0 * 32 + jl]);
      float s1 = Gt2[(1 * 2 + w) * 64 + lane] + bf2f(GxL[gxb][bq * 128 + 1 * 32 + jl]);
      float s2 = Gt2[(2 * 2 + w) * 64 + lane] + bf2f(GxL[gxb][bq * 128 + 2 * 32 + jl]);
      float s3 = Gt2[(3 * 2 + w) * 64 + lane] + bf2f(GxL[gxb][bq * 128 + 3 * 32 + jl]);
      float ia = sigm(s0), fa = sigm(s1), ga = tanh_(s2), oa = sigm(s3);
      c = fa * c + ia * ga;
      float h = oa * tanh_(c);
      if (more) {
        unsigned short hb = f2bf(h);
        unsigned int word = (unsigned int)hb | (((unsigned int)(t + 1)) << 16);
        unsigned int* qL = ((t + 1) & 1) ? pubL1 : pubL0;
        unsigned int* qM = ((t + 1) & 1) ? pubM1 : pubM0;
        // L: plain (stays dirty+live in shared local L2; sc0 polls hit it)
        asm volatile("global_store_dword %0, %1, off" :: "v"(qL), "v"(word) : "memory");
        // M: sc0sc1 (MALL mirror, correctness for misplaced WGs)
        asm volatile("global_store_dword %0, %1, off sc0 sc1" :: "v"(qM), "v"(word) : "memory");
        As[bq * 536 + col] = hb;  // self-inject own h(t+1) into LDS
        pfa = fa; ph = h; pga = ga;
      } else {
        size_t bo = (size_t)bno * (T_ * H_) + (size_t)t * H_ + col;
        asm volatile("global_store_dword %0, %1, off" :: "v"(out + bo), "v"(fa) : "memory");
        asm volatile("global_store_dword %0, %1, off"
                     :: "v"(out + BTH + bo), "v"(h) : "memory");
        asm volatile("global_store_dword %0, %1, off"
                     :: "v"(out + 2 * BTH + bo), "v"(ga) : "memory");
        out[3 * BTH + (size_t)bno * H_ + col] = oa;
      }
    }
    if (more) {
      // wave FIFO at check:
      //  w==0: [outs3][gxr][pollF][pubL][pubM] -> VMWAIT(2) retires pollF
      //  w==1: [outs3][pollF][pubL][pubM]      -> VMWAIT(2)
      //  w>=2: [pollF]                         -> VMWAIT(0)
      if (w < 2) VMWAIT(2); else VMWAIT(0);
      const unsigned want = (unsigned)(t + 1);
      unsigned bad = 0u;
      if (!ownq)
        bad = ((hv[0] >> 16) ^ want) | ((hv[1] >> 16) ^ want) |
              ((hv[2] >> 16) ^ want) | ((hv[3] >> 16) ^ want);
      int guard = 0;
      while (bad) {
        if (++guard < 4) POLLF(pollL); else POLLS(pollM);
        VMWAIT(0);
        bad = ((hv[0] >> 16) ^ want) | ((hv[1] >> 16) ^ want) |
              ((hv[2] >> 16) ^ want) | ((hv[3] >> 16) ^ want);
        if (guard > (1 << 20)) break;
      }
      if (!ownq) {
        uint2v pk;
        pk[0] = (hv[0] & 0xffffu) | (hv[1] << 16);
        pk[1] = (hv[2] & 0xffffu) | (hv[3] << 16);
        *reinterpret_cast<uint2v*>(&As[(tid >> 7) * 536 + (tid & 127) * 4]) = pk;
      }
      if (w == 0)
        *reinterpret_cast<uint4v*>(&GxL[(t + 1) & 1][lane * 8]) = __builtin_bit_cast(uint4v, gxr);
    }
  }
}

extern "C" void kernel_launch(void* const* d_in, const int* in_sizes, int n_in,
                              void* d_out, int out_size, void* d_ws, size_t ws_size,
                              hipStream_t stream) {
  const float* x    = (const float*)d_in[0];
  const float* hx   = (const float*)d_in[1];
  const float* cx   = (const float*)d_in[2];
  const float* w_ih = (const float*)d_in[3];
  const float* w_hh = (const float*)d_in[4];
  const float* b_ih = (const float*)d_in[5];
  const float* b_hh = (const float*)d_in[6];
  float* out = (float*)d_out;
  char* ws = (char*)d_ws;
  const size_t OFF_XBF  = 0;                    // 67,108,864
  const size_t OFF_WBF  = 67108864;             //  2,097,152
  const size_t OFF_GX   = 69206016;             // 268,435,456
  const size_t OFF_HTAG = 337641472;            //    262,144 (L + M)
  const size_t OFF_CTRL = 337903616;            //      4,096
  const size_t NEEDED   = 337907712;
  if (ws_size < NEEDED) return;

  unsigned short* x_bf  = (unsigned short*)(ws + OFF_XBF);
  unsigned short* w_bf  = (unsigned short*)(ws + OFF_WBF);
  unsigned short* gx_ws = (unsigned short*)(ws + OFF_GX);
  unsigned int*   h_tag = (unsigned int*)(ws + OFF_HTAG);
  unsigned int*   ctrl  = (unsigned int*)(ws + OFF_CTRL);

  prep_kernel<<<16913, 256, 0, stream>>>(x, w_ih, hx, x_bf, w_bf, h_tag, ctrl);
  gemm_gx<<<8192, 256, 0, stream>>>(x_bf, w_bf, b_ih, b_hh, gx_ws);
  lstm_rec<<<128, 512, 0, stream>>>(cx, w_hh, gx_ws, h_tag, ctrl, out);
}